// Round 1
// baseline (4359.281 us; speedup 1.0000x reference)
//
#include <hip/hip_runtime.h>

typedef unsigned short ushort_t;
typedef unsigned int uint_t;

using f16x8 = __attribute__((ext_vector_type(8))) _Float16;
using f16x2 = __attribute__((ext_vector_type(2))) _Float16;
using f32x4 = __attribute__((ext_vector_type(4))) float;

#define BATCH 64
#define SEQT 512
#define DIN 256
#define HID 256
#define G4 1024   // 4*HID

static __device__ __forceinline__ ushort_t f16b(float x) {
    return __builtin_bit_cast(ushort_t, (_Float16)x);
}
static __device__ __forceinline__ uint_t pk2(float a, float b) {
    return (uint_t)f16b(a) | ((uint_t)f16b(b) << 16);
}
static __device__ __forceinline__ float sigmoidf_(float x) {
    return 1.f / (1.f + expf(-x));
}

// ---------------- prep kernels ----------------

// x f32 -> f16 bits, 4 elems/thread
__global__ void cvt_x_kernel(const float* __restrict__ in, ushort_t* __restrict__ out, int n4) {
    int i = blockIdx.x * blockDim.x + threadIdx.x;
    if (i < n4) {
        float4 v = ((const float4*)in)[i];
        ushort4 o;
        o.x = f16b(v.x); o.y = f16b(v.y); o.z = f16b(v.z); o.w = f16b(v.w);
        ((ushort4*)out)[i] = o;
    }
}

// W [256][1024] f32 -> Wt [1024][256] f16 bits (transpose)
__global__ void prep_wt_kernel(const float* __restrict__ W, ushort_t* __restrict__ Wt) {
    int tid = blockIdx.x * blockDim.x + threadIdx.x; // 262144
    int k = tid >> 10;
    int n = tid & 1023;
    Wt[n * DIN + k] = f16b(W[tid]);
}

// U [256][1024] f32 -> Upk [32][1024] uint4; Upk[j][g] holds f16 pairs for k=8j..8j+7, col g
__global__ void prep_upk_kernel(const float* __restrict__ U, uint4* __restrict__ Upk) {
    int tid = blockIdx.x * blockDim.x + threadIdx.x; // 32768
    int j = tid >> 10;
    int g = tid & 1023;
    uint4 o;
    uint_t* op = &o.x;
#pragma unroll
    for (int q = 0; q < 4; ++q) {
        float a = U[(8 * j + 2 * q) * G4 + g];
        float b = U[(8 * j + 2 * q + 1) * G4 + g];
        op[q] = pk2(a, b);
    }
    Upk[tid] = o;
}

// ---------------- GEMM: C[M][1024] = A[M][256](f16) @ Bt[1024][256](f16)^T + bias ----------------
// 128x128 tile, 4 waves, BK=32, mfma_f32_16x16x32_f16

#define GSTRIDE 40  // 32 + 8 pad (ushorts); 80B rows, 16B-aligned sub-chunks

__global__ __launch_bounds__(256) void gemm_f16_kernel(
    const ushort_t* __restrict__ A,   // [M][256]
    const ushort_t* __restrict__ Bt,  // [1024][256]
    const float* __restrict__ bias,   // [1024]
    float* __restrict__ C,            // [M][1024]
    int M)
{
    const int K = DIN, N = G4;
    __shared__ ushort_t As[128 * GSTRIDE];
    __shared__ ushort_t Bs[128 * GSTRIDE];
    int tid = threadIdx.x;
    int bx = blockIdx.x & 7;       // N/128 = 8
    int by = blockIdx.x >> 3;
    int m0 = by * 128, n0 = bx * 128;
    int w = tid >> 6, lane = tid & 63;
    int wr = (w >> 1) * 64, wc = (w & 1) * 64;
    int r = lane & 15, kg = lane >> 4;

    f32x4 acc[4][4];
#pragma unroll
    for (int i = 0; i < 4; ++i)
#pragma unroll
        for (int j = 0; j < 4; ++j)
            acc[i][j] = f32x4{0.f, 0.f, 0.f, 0.f};

    for (int kt = 0; kt < K; kt += 32) {
        __syncthreads();
#pragma unroll
        for (int s = 0; s < 2; ++s) {
            int chunk = tid + s * 256;       // 0..511
            int row = chunk >> 2;
            int ko = (chunk & 3) * 8;
            uint4 va = *(const uint4*)(A + (size_t)(m0 + row) * K + kt + ko);
            *(uint4*)(&As[row * GSTRIDE + ko]) = va;
            uint4 vb = *(const uint4*)(Bt + (size_t)(n0 + row) * K + kt + ko);
            *(uint4*)(&Bs[row * GSTRIDE + ko]) = vb;
        }
        __syncthreads();
        f16x8 af[4], bf[4];
#pragma unroll
        for (int i = 0; i < 4; ++i) {
            af[i] = *(const f16x8*)(&As[(wr + i * 16 + r) * GSTRIDE + kg * 8]);
            bf[i] = *(const f16x8*)(&Bs[(wc + i * 16 + r) * GSTRIDE + kg * 8]);
        }
#pragma unroll
        for (int i = 0; i < 4; ++i)
#pragma unroll
            for (int j = 0; j < 4; ++j)
                acc[i][j] = __builtin_amdgcn_mfma_f32_16x16x32_f16(af[i], bf[j], acc[i][j], 0, 0, 0);
    }

    // epilogue: D row=(lane>>4)*4+v, col=lane&15  (m89-verified layout)
#pragma unroll
    for (int i = 0; i < 4; ++i)
#pragma unroll
        for (int j = 0; j < 4; ++j) {
            int col = n0 + wc + j * 16 + r;
            float bv = bias[col];
#pragma unroll
            for (int v = 0; v < 4; ++v) {
                int rowg = m0 + wr + i * 16 + kg * 4 + v;
                C[(size_t)rowg * N + col] = acc[i][j][v] + bv;
            }
        }
}

// ---------------- LSTM recurrence: one WG per batch row ----------------
// xz [B*T][1024] f32 (bias already included), Upk [32][1024] uint4 (f16 pairs)
// out: either f16 bits [B*T][256] (layer 1) or f32 (final layer)

__global__ __launch_bounds__(1024) void lstm_rec_kernel(
    const float* __restrict__ xz,
    const uint4* __restrict__ Upk,
    ushort_t* __restrict__ out_h16,
    float* __restrict__ out_f32,
    int T)
{
    __shared__ ushort_t h16[HID];
    __shared__ float zbuf[G4];
    __shared__ uint4 Ulds[3 * 1024];   // first 3 j-rows of Upk (48 KB)

    int g = threadIdx.x;
    int b = blockIdx.x;

    if (g < HID) h16[g] = 0;
#pragma unroll
    for (int q = 0; q < 3; ++q) Ulds[q * 1024 + g] = Upk[q * 1024 + g];
    float c = 0.f;
    __syncthreads();

    const uint_t* hp = (const uint_t*)h16;

    for (int t = 0; t < T; ++t) {
        float z = xz[((size_t)b * T + t) * G4 + g];

        // j-rows 0..2 from LDS
#pragma unroll
        for (int j = 0; j < 3; ++j) {
            uint4 u = Ulds[j * 1024 + g];
            const uint_t* up = &u.x;
#pragma unroll
            for (int q = 0; q < 4; ++q) {
                f16x2 hv = __builtin_bit_cast(f16x2, hp[j * 4 + q]);
                f16x2 uv = __builtin_bit_cast(f16x2, up[q]);
#if __has_builtin(__builtin_amdgcn_fdot2)
                z = __builtin_amdgcn_fdot2(hv, uv, z, false);
#else
                z += (float)hv.x * (float)uv.x + (float)hv.y * (float)uv.y;
#endif
            }
        }
        // j-rows 3..31 from global (L2-resident)
#pragma unroll 4
        for (int j = 3; j < 32; ++j) {
            uint4 u = Upk[j * 1024 + g];
            const uint_t* up = &u.x;
#pragma unroll
            for (int q = 0; q < 4; ++q) {
                f16x2 hv = __builtin_bit_cast(f16x2, hp[j * 4 + q]);
                f16x2 uv = __builtin_bit_cast(f16x2, up[q]);
#if __has_builtin(__builtin_amdgcn_fdot2)
                z = __builtin_amdgcn_fdot2(hv, uv, z, false);
#else
                z += (float)hv.x * (float)uv.x + (float)hv.y * (float)uv.y;
#endif
            }
        }

        zbuf[g] = z;
        __syncthreads();

        if (g < HID) {
            float iv = zbuf[g];
            float fv = zbuf[g + HID];
            float gv = zbuf[g + 2 * HID];
            float ov = zbuf[g + 3 * HID];
            c = sigmoidf_(fv) * c + sigmoidf_(iv) * tanhf(gv);
            float h = sigmoidf_(ov) * tanhf(c);
            size_t oi = ((size_t)b * T + t) * HID + g;
            if (out_f32) out_f32[oi] = h;
            else out_h16[oi] = f16b(h);
            h16[g] = f16b(h);
        }
        __syncthreads();
    }
}

// ---------------- launch ----------------

extern "C" void kernel_launch(void* const* d_in, const int* in_sizes, int n_in,
                              void* d_out, int out_size, void* d_ws, size_t ws_size,
                              hipStream_t stream) {
    const float* x  = (const float*)d_in[0];
    const float* W0 = (const float*)d_in[1];
    const float* U0 = (const float*)d_in[2];
    const float* b0 = (const float*)d_in[3];
    const float* W1 = (const float*)d_in[4];
    const float* U1 = (const float*)d_in[5];
    const float* b1 = (const float*)d_in[6];
    float* out = (float*)d_out;

    const size_t M = (size_t)BATCH * SEQT;   // 32768

    // workspace layout (bytes)
    char* ws = (char*)d_ws;
    ushort_t* xf16  = (ushort_t*)(ws);                        // 16 MB
    ushort_t* y1f16 = (ushort_t*)(ws + (16u << 20));          // 16 MB
    ushort_t* Wt0   = (ushort_t*)(ws + (32u << 20));          // 0.5 MB
    ushort_t* Wt1   = (ushort_t*)(ws + (32u << 20) + 524288); // 0.5 MB
    uint4*    Upk0  = (uint4*)   (ws + (33u << 20));          // 0.5 MB
    uint4*    Upk1  = (uint4*)   (ws + (33u << 20) + 524288); // 0.5 MB
    float*    xz    = (float*)   (ws + (34u << 20));          // 128 MB

    // prep
    {
        int n4 = (int)(M * DIN / 4);   // 2097152
        cvt_x_kernel<<<dim3((n4 + 255) / 256), dim3(256), 0, stream>>>(x, xf16, n4);
        prep_wt_kernel<<<dim3(1024), dim3(256), 0, stream>>>(W0, Wt0);
        prep_wt_kernel<<<dim3(1024), dim3(256), 0, stream>>>(W1, Wt1);
        prep_upk_kernel<<<dim3(128), dim3(256), 0, stream>>>(U0, Upk0);
        prep_upk_kernel<<<dim3(128), dim3(256), 0, stream>>>(U1, Upk1);
    }

    // layer 1
    gemm_f16_kernel<<<dim3((int)(M / 128) * 8), dim3(256), 0, stream>>>(xf16, Wt0, b0, xz, (int)M);
    lstm_rec_kernel<<<dim3(BATCH), dim3(1024), 0, stream>>>(xz, Upk0, y1f16, nullptr, SEQT);

    // layer 2
    gemm_f16_kernel<<<dim3((int)(M / 128) * 8), dim3(256), 0, stream>>>(y1f16, Wt1, b1, xz, (int)M);
    lstm_rec_kernel<<<dim3(BATCH), dim3(1024), 0, stream>>>(xz, Upk1, nullptr, out, SEQT);
}

// Round 2
// 2370.656 us; speedup vs baseline: 1.8388x; 1.8388x over previous
//
#include <hip/hip_runtime.h>

typedef unsigned short ushort_t;
typedef unsigned int uint_t;

using f16x8 = __attribute__((ext_vector_type(8))) _Float16;
using f16x2 = __attribute__((ext_vector_type(2))) _Float16;
using f32x4 = __attribute__((ext_vector_type(4))) float;

#define BATCH 64
#define SEQT 512
#define DIN 256
#define HID 256
#define G4 1024   // 4*HID

#define RCH 24    // U k-chunks held in registers (per column)
#define LCH 8     // U k-chunks held in LDS

static __device__ __forceinline__ ushort_t f16b(float x) {
    return __builtin_bit_cast(ushort_t, (_Float16)x);
}
static __device__ __forceinline__ uint_t pk2(float a, float b) {
    return (uint_t)f16b(a) | ((uint_t)f16b(b) << 16);
}
static __device__ __forceinline__ float sig_(float x) {
    return 1.f / (1.f + __expf(-x));
}
static __device__ __forceinline__ float tanh_(float x) {
    // tanh(x) = 1 - 2/(exp(2x)+1), numerically fine for |x| up to ~44 with __expf
    float e = __expf(2.f * x);
    return (e - 1.f) / (e + 1.f);
}

// fdot2 pair-of-4: z += dot(u, h) over 8 f16 values
static __device__ __forceinline__ void dot8(float& z, const uint4& u, const uint4& h) {
    const uint_t* up = &u.x;
    const uint_t* hp = &h.x;
#pragma unroll
    for (int q = 0; q < 4; ++q) {
        f16x2 hv = __builtin_bit_cast(f16x2, hp[q]);
        f16x2 uv = __builtin_bit_cast(f16x2, up[q]);
#if __has_builtin(__builtin_amdgcn_fdot2)
        z = __builtin_amdgcn_fdot2(hv, uv, z, false);
#else
        z += (float)hv.x * (float)uv.x + (float)hv.y * (float)uv.y;
#endif
    }
}

// ---------------- prep kernels ----------------

__global__ void cvt_x_kernel(const float* __restrict__ in, ushort_t* __restrict__ out, int n4) {
    int i = blockIdx.x * blockDim.x + threadIdx.x;
    if (i < n4) {
        float4 v = ((const float4*)in)[i];
        ushort4 o;
        o.x = f16b(v.x); o.y = f16b(v.y); o.z = f16b(v.z); o.w = f16b(v.w);
        ((ushort4*)out)[i] = o;
    }
}

// W [256][1024] f32 -> Wt [1024][256] f16 bits (transpose)
__global__ void prep_wt_kernel(const float* __restrict__ W, ushort_t* __restrict__ Wt) {
    int tid = blockIdx.x * blockDim.x + threadIdx.x; // 262144
    int k = tid >> 10;
    int n = tid & 1023;
    Wt[n * DIN + k] = f16b(W[tid]);
}

// U [256][1024] f32 -> Upk [32][1024] uint4; Upk[j][g] holds f16 pairs for k=8j..8j+7, col g
__global__ void prep_upk_kernel(const float* __restrict__ U, uint4* __restrict__ Upk) {
    int tid = blockIdx.x * blockDim.x + threadIdx.x; // 32768
    int j = tid >> 10;
    int g = tid & 1023;
    uint4 o;
    uint_t* op = &o.x;
#pragma unroll
    for (int q = 0; q < 4; ++q) {
        float a = U[(8 * j + 2 * q) * G4 + g];
        float b = U[(8 * j + 2 * q + 1) * G4 + g];
        op[q] = pk2(a, b);
    }
    Upk[tid] = o;
}

// ---------------- GEMM: C[M][1024] = A[M][256](f16) @ Bt[1024][256](f16)^T + bias ----------------

#define GSTRIDE 40  // 32 + 8 pad (ushorts)

__global__ __launch_bounds__(256) void gemm_f16_kernel(
    const ushort_t* __restrict__ A,   // [M][256]
    const ushort_t* __restrict__ Bt,  // [1024][256]
    const float* __restrict__ bias,   // [1024]
    float* __restrict__ C,            // [M][1024]
    int M)
{
    const int K = DIN, N = G4;
    __shared__ ushort_t As[128 * GSTRIDE];
    __shared__ ushort_t Bs[128 * GSTRIDE];
    int tid = threadIdx.x;
    int bx = blockIdx.x & 7;
    int by = blockIdx.x >> 3;
    int m0 = by * 128, n0 = bx * 128;
    int w = tid >> 6, lane = tid & 63;
    int wr = (w >> 1) * 64, wc = (w & 1) * 64;
    int r = lane & 15, kg = lane >> 4;

    f32x4 acc[4][4];
#pragma unroll
    for (int i = 0; i < 4; ++i)
#pragma unroll
        for (int j = 0; j < 4; ++j)
            acc[i][j] = f32x4{0.f, 0.f, 0.f, 0.f};

    for (int kt = 0; kt < K; kt += 32) {
        __syncthreads();
#pragma unroll
        for (int s = 0; s < 2; ++s) {
            int chunk = tid + s * 256;
            int row = chunk >> 2;
            int ko = (chunk & 3) * 8;
            uint4 va = *(const uint4*)(A + (size_t)(m0 + row) * K + kt + ko);
            *(uint4*)(&As[row * GSTRIDE + ko]) = va;
            uint4 vb = *(const uint4*)(Bt + (size_t)(n0 + row) * K + kt + ko);
            *(uint4*)(&Bs[row * GSTRIDE + ko]) = vb;
        }
        __syncthreads();
        f16x8 af[4], bf[4];
#pragma unroll
        for (int i = 0; i < 4; ++i) {
            af[i] = *(const f16x8*)(&As[(wr + i * 16 + r) * GSTRIDE + kg * 8]);
            bf[i] = *(const f16x8*)(&Bs[(wc + i * 16 + r) * GSTRIDE + kg * 8]);
        }
#pragma unroll
        for (int i = 0; i < 4; ++i)
#pragma unroll
            for (int j = 0; j < 4; ++j)
                acc[i][j] = __builtin_amdgcn_mfma_f32_16x16x32_f16(af[i], bf[j], acc[i][j], 0, 0, 0);
    }

#pragma unroll
    for (int i = 0; i < 4; ++i)
#pragma unroll
        for (int j = 0; j < 4; ++j) {
            int col = n0 + wc + j * 16 + r;
            float bv = bias[col];
#pragma unroll
            for (int v = 0; v < 4; ++v) {
                int rowg = m0 + wr + i * 16 + kg * 4 + v;
                C[(size_t)rowg * N + col] = acc[i][j][v] + bv;
            }
        }
}

// ---------------- LSTM recurrence: one WG (512 thr, 8 waves) per batch row ----------------
// U fully CU-resident: 24 chunks in registers (per column), 8 chunks in LDS.

__global__ __launch_bounds__(512, 2) void lstm_rec2_kernel(
    const float* __restrict__ xz,     // [B*T][1024], bias included
    const uint4* __restrict__ Upk,    // [32][1024]
    ushort_t* __restrict__ out_h16,
    float* __restrict__ out_f32,
    int T)
{
    __shared__ uint4 Ulds[LCH * 1024];        // 128 KB
    __shared__ float zbuf[G4];                // 4 KB
    __shared__ uint_t h32[HID / 2];           // 512 B (h as f16 pairs)

    int tid = threadIdx.x;        // 0..511
    int b = blockIdx.x;
    int g0 = tid;
    int g1 = tid + 512;

    // stage LDS-held U chunks (j = RCH..31): 8192 uint4
#pragma unroll
    for (int s = 0; s < 16; ++s) {
        int idx = s * 512 + tid;
        Ulds[idx] = Upk[RCH * 1024 + idx];
    }
    if (tid < HID / 2) h32[tid] = 0;

    // preload register-held U chunks
    uint4 ur0[RCH], ur1[RCH];
#pragma unroll
    for (int j = 0; j < RCH; ++j) {
        ur0[j] = Upk[j * 1024 + g0];
        ur1[j] = Upk[j * 1024 + g1];
    }
    float c = 0.f;
    __syncthreads();

    const uint4* hp4 = (const uint4*)h32;     // 32 x 16B broadcast chunks

    for (int t = 0; t < T; ++t) {
        const float* xzt = xz + ((size_t)b * T + t) * G4;
        float z0a = xzt[g0];                  // independent of h: issues early
        float z1a = xzt[g1];
        float z0b = 0.f, z1b = 0.f;           // 4 accumulator chains

#pragma unroll
        for (int j = 0; j < RCH; j += 2) {
            uint4 h0 = hp4[j];
            uint4 h1 = hp4[j + 1];
            dot8(z0a, ur0[j], h0);
            dot8(z1a, ur1[j], h0);
            dot8(z0b, ur0[j + 1], h1);
            dot8(z1b, ur1[j + 1], h1);
        }
#pragma unroll
        for (int j = 0; j < LCH; j += 2) {
            uint4 h0 = hp4[RCH + j];
            uint4 h1 = hp4[RCH + j + 1];
            uint4 u00 = Ulds[j * 1024 + g0];
            uint4 u01 = Ulds[j * 1024 + g1];
            uint4 u10 = Ulds[(j + 1) * 1024 + g0];
            uint4 u11 = Ulds[(j + 1) * 1024 + g1];
            dot8(z0a, u00, h0);
            dot8(z1a, u01, h0);
            dot8(z0b, u10, h1);
            dot8(z1b, u11, h1);
        }
        zbuf[g0] = z0a + z0b;
        zbuf[g1] = z1a + z1b;
        __syncthreads();

        if (tid < HID) {
            float iv = zbuf[tid];
            float fv = zbuf[tid + HID];
            float gv = zbuf[tid + 2 * HID];
            float ov = zbuf[tid + 3 * HID];
            c = sig_(fv) * c + sig_(iv) * tanh_(gv);
            float h = sig_(ov) * tanh_(c);
            size_t oi = ((size_t)b * T + t) * HID + tid;
            if (out_f32) out_f32[oi] = h;
            else out_h16[oi] = f16b(h);
            ((ushort_t*)h32)[tid] = f16b(h);
        }
        __syncthreads();
    }
}

// ---------------- launch ----------------

extern "C" void kernel_launch(void* const* d_in, const int* in_sizes, int n_in,
                              void* d_out, int out_size, void* d_ws, size_t ws_size,
                              hipStream_t stream) {
    const float* x  = (const float*)d_in[0];
    const float* W0 = (const float*)d_in[1];
    const float* U0 = (const float*)d_in[2];
    const float* b0 = (const float*)d_in[3];
    const float* W1 = (const float*)d_in[4];
    const float* U1 = (const float*)d_in[5];
    const float* b1 = (const float*)d_in[6];
    float* out = (float*)d_out;

    const size_t M = (size_t)BATCH * SEQT;   // 32768

    char* ws = (char*)d_ws;
    ushort_t* xf16  = (ushort_t*)(ws);                        // 16 MB
    ushort_t* y1f16 = (ushort_t*)(ws + (16u << 20));          // 16 MB
    ushort_t* Wt0   = (ushort_t*)(ws + (32u << 20));          // 0.5 MB
    ushort_t* Wt1   = (ushort_t*)(ws + (32u << 20) + 524288); // 0.5 MB
    uint4*    Upk0  = (uint4*)   (ws + (33u << 20));          // 0.5 MB
    uint4*    Upk1  = (uint4*)   (ws + (33u << 20) + 524288); // 0.5 MB
    float*    xz    = (float*)   (ws + (34u << 20));          // 128 MB

    {
        int n4 = (int)(M * DIN / 4);
        cvt_x_kernel<<<dim3((n4 + 255) / 256), dim3(256), 0, stream>>>(x, xf16, n4);
        prep_wt_kernel<<<dim3(1024), dim3(256), 0, stream>>>(W0, Wt0);
        prep_wt_kernel<<<dim3(1024), dim3(256), 0, stream>>>(W1, Wt1);
        prep_upk_kernel<<<dim3(128), dim3(256), 0, stream>>>(U0, Upk0);
        prep_upk_kernel<<<dim3(128), dim3(256), 0, stream>>>(U1, Upk1);
    }

    // layer 1
    gemm_f16_kernel<<<dim3((int)(M / 128) * 8), dim3(256), 0, stream>>>(xf16, Wt0, b0, xz, (int)M);
    lstm_rec2_kernel<<<dim3(BATCH), dim3(512), 0, stream>>>(xz, Upk0, y1f16, nullptr, SEQT);

    // layer 2
    gemm_f16_kernel<<<dim3((int)(M / 128) * 8), dim3(256), 0, stream>>>(y1f16, Wt1, b1, xz, (int)M);
    lstm_rec2_kernel<<<dim3(BATCH), dim3(512), 0, stream>>>(xz, Upk1, nullptr, out, SEQT);
}

// Round 3
// 2230.594 us; speedup vs baseline: 1.9543x; 1.0628x over previous
//
#include <hip/hip_runtime.h>

typedef unsigned short ushort_t;
typedef unsigned int uint_t;

using f16x8 = __attribute__((ext_vector_type(8))) _Float16;
using f16x2 = __attribute__((ext_vector_type(2))) _Float16;
using f32x4 = __attribute__((ext_vector_type(4))) float;

#define BATCH 64
#define SEQT 512
#define DIN 256
#define HID 256
#define G4 1024   // 4*HID

#define RCH 24    // U k-chunks held in registers (per column)
#define LCH 8     // U k-chunks held in LDS

// Opaque value barrier: compiler cannot rematerialize these from memory.
#define PIN4(v) asm volatile("" : "+v"((v).x), "+v"((v).y), "+v"((v).z), "+v"((v).w))

static __device__ __forceinline__ ushort_t f16b(float x) {
    return __builtin_bit_cast(ushort_t, (_Float16)x);
}
static __device__ __forceinline__ uint_t pk2(float a, float b) {
    return (uint_t)f16b(a) | ((uint_t)f16b(b) << 16);
}
static __device__ __forceinline__ float sig_(float x) {
    return 1.f / (1.f + __expf(-x));
}
static __device__ __forceinline__ float tanh_(float x) {
    float e = __expf(2.f * x);
    return (e - 1.f) / (e + 1.f);
}

// z += dot(u, h) over 8 f16 values
static __device__ __forceinline__ void dot8(float& z, const uint4& u, const uint4& h) {
    const uint_t* up = &u.x;
    const uint_t* hp = &h.x;
#pragma unroll
    for (int q = 0; q < 4; ++q) {
        f16x2 hv = __builtin_bit_cast(f16x2, hp[q]);
        f16x2 uv = __builtin_bit_cast(f16x2, up[q]);
#if __has_builtin(__builtin_amdgcn_fdot2)
        z = __builtin_amdgcn_fdot2(hv, uv, z, false);
#else
        z += (float)hv.x * (float)uv.x + (float)hv.y * (float)uv.y;
#endif
    }
}

// ---------------- prep kernels ----------------

__global__ void cvt_x_kernel(const float* __restrict__ in, ushort_t* __restrict__ out, int n4) {
    int i = blockIdx.x * blockDim.x + threadIdx.x;
    if (i < n4) {
        float4 v = ((const float4*)in)[i];
        ushort4 o;
        o.x = f16b(v.x); o.y = f16b(v.y); o.z = f16b(v.z); o.w = f16b(v.w);
        ((ushort4*)out)[i] = o;
    }
}

// W [256][1024] f32 -> Wt [1024][256] f16 bits (transpose)
__global__ void prep_wt_kernel(const float* __restrict__ W, ushort_t* __restrict__ Wt) {
    int tid = blockIdx.x * blockDim.x + threadIdx.x;
    int k = tid >> 10;
    int n = tid & 1023;
    Wt[n * DIN + k] = f16b(W[tid]);
}

// U [256][1024] f32 -> Upk [32][1024] uint4
__global__ void prep_upk_kernel(const float* __restrict__ U, uint4* __restrict__ Upk) {
    int tid = blockIdx.x * blockDim.x + threadIdx.x;
    int j = tid >> 10;
    int g = tid & 1023;
    uint4 o;
    uint_t* op = &o.x;
#pragma unroll
    for (int q = 0; q < 4; ++q) {
        float a = U[(8 * j + 2 * q) * G4 + g];
        float b = U[(8 * j + 2 * q + 1) * G4 + g];
        op[q] = pk2(a, b);
    }
    Upk[tid] = o;
}

// ---------------- GEMM ----------------

#define GSTRIDE 40

__global__ __launch_bounds__(256) void gemm_f16_kernel(
    const ushort_t* __restrict__ A,
    const ushort_t* __restrict__ Bt,
    const float* __restrict__ bias,
    float* __restrict__ C,
    int M)
{
    const int K = DIN, N = G4;
    __shared__ ushort_t As[128 * GSTRIDE];
    __shared__ ushort_t Bs[128 * GSTRIDE];
    int tid = threadIdx.x;
    int bx = blockIdx.x & 7;
    int by = blockIdx.x >> 3;
    int m0 = by * 128, n0 = bx * 128;
    int w = tid >> 6, lane = tid & 63;
    int wr = (w >> 1) * 64, wc = (w & 1) * 64;
    int r = lane & 15, kg = lane >> 4;

    f32x4 acc[4][4];
#pragma unroll
    for (int i = 0; i < 4; ++i)
#pragma unroll
        for (int j = 0; j < 4; ++j)
            acc[i][j] = f32x4{0.f, 0.f, 0.f, 0.f};

    for (int kt = 0; kt < K; kt += 32) {
        __syncthreads();
#pragma unroll
        for (int s = 0; s < 2; ++s) {
            int chunk = tid + s * 256;
            int row = chunk >> 2;
            int ko = (chunk & 3) * 8;
            uint4 va = *(const uint4*)(A + (size_t)(m0 + row) * K + kt + ko);
            *(uint4*)(&As[row * GSTRIDE + ko]) = va;
            uint4 vb = *(const uint4*)(Bt + (size_t)(n0 + row) * K + kt + ko);
            *(uint4*)(&Bs[row * GSTRIDE + ko]) = vb;
        }
        __syncthreads();
        f16x8 af[4], bf[4];
#pragma unroll
        for (int i = 0; i < 4; ++i) {
            af[i] = *(const f16x8*)(&As[(wr + i * 16 + r) * GSTRIDE + kg * 8]);
            bf[i] = *(const f16x8*)(&Bs[(wc + i * 16 + r) * GSTRIDE + kg * 8]);
        }
#pragma unroll
        for (int i = 0; i < 4; ++i)
#pragma unroll
            for (int j = 0; j < 4; ++j)
                acc[i][j] = __builtin_amdgcn_mfma_f32_16x16x32_f16(af[i], bf[j], acc[i][j], 0, 0, 0);
    }

#pragma unroll
    for (int i = 0; i < 4; ++i)
#pragma unroll
        for (int j = 0; j < 4; ++j) {
            int col = n0 + wc + j * 16 + r;
            float bv = bias[col];
#pragma unroll
            for (int v = 0; v < 4; ++v) {
                int rowg = m0 + wr + i * 16 + kg * 4 + v;
                C[(size_t)rowg * N + col] = acc[i][j][v] + bv;
            }
        }
}

// ---------------- LSTM recurrence: one WG (512 thr, 8 waves) per batch row ----------------
// U CU-resident: 24 chunks pinned in registers (per column), 8 chunks in LDS.

__global__ __launch_bounds__(512, 2) void lstm_rec3_kernel(
    const float* __restrict__ xz,     // [B*T][1024], bias included
    const uint4* __restrict__ Upk,    // [32][1024]
    ushort_t* __restrict__ out_h16,
    float* __restrict__ out_f32,
    int T)
{
    __shared__ uint4 Ulds[LCH * 1024];        // 128 KB
    __shared__ float zbuf[G4];                // 4 KB
    __shared__ uint_t h32[HID / 2];           // 512 B

    int tid = threadIdx.x;        // 0..511
    int b = blockIdx.x;
    int g0 = tid;
    int g1 = tid + 512;

    // stage LDS-held U chunks (j = RCH..31)
#pragma unroll
    for (int s = 0; s < 16; ++s) {
        int idx = s * 512 + tid;
        Ulds[idx] = Upk[RCH * 1024 + idx];
    }
    if (tid < HID / 2) h32[tid] = 0;

    // preload register-held U chunks, then pin them (no rematerialization)
    uint4 ur0[RCH], ur1[RCH];
#pragma unroll
    for (int j = 0; j < RCH; ++j) {
        ur0[j] = Upk[j * 1024 + g0];
        ur1[j] = Upk[j * 1024 + g1];
    }
#pragma unroll
    for (int j = 0; j < RCH; ++j) {
        PIN4(ur0[j]);
        PIN4(ur1[j]);
    }
    float c = 0.f;
    __syncthreads();

    const uint4* hp4 = (const uint4*)h32;

    // prefetch xz for t=0
    const float* xz_b = xz + (size_t)b * T * G4;
    float xzp0 = xz_b[g0];
    float xzp1 = xz_b[g1];

    for (int t = 0; t < T; ++t) {
        float z0a = xzp0, z1a = xzp1;
        float z0b = 0.f, z1b = 0.f;

        // prefetch next step's xz early — latency hides under the dot loop
        if (t + 1 < T) {
            const float* xzn = xz_b + (size_t)(t + 1) * G4;
            xzp0 = xzn[g0];
            xzp1 = xzn[g1];
        }

#pragma unroll
        for (int j = 0; j < RCH; j += 2) {
            uint4 h0 = hp4[j];
            uint4 h1 = hp4[j + 1];
            dot8(z0a, ur0[j], h0);
            dot8(z1a, ur1[j], h0);
            dot8(z0b, ur0[j + 1], h1);
            dot8(z1b, ur1[j + 1], h1);
        }
#pragma unroll
        for (int j = 0; j < LCH; j += 2) {
            uint4 h0 = hp4[RCH + j];
            uint4 h1 = hp4[RCH + j + 1];
            uint4 u00 = Ulds[j * 1024 + g0];
            uint4 u01 = Ulds[j * 1024 + g1];
            uint4 u10 = Ulds[(j + 1) * 1024 + g0];
            uint4 u11 = Ulds[(j + 1) * 1024 + g1];
            dot8(z0a, u00, h0);
            dot8(z1a, u01, h0);
            dot8(z0b, u10, h1);
            dot8(z1b, u11, h1);
        }
        zbuf[g0] = z0a + z0b;
        zbuf[g1] = z1a + z1b;
        __syncthreads();

        if (tid < HID) {
            float iv = zbuf[tid];
            float fv = zbuf[tid + HID];
            float gv = zbuf[tid + 2 * HID];
            float ov = zbuf[tid + 3 * HID];
            c = sig_(fv) * c + sig_(iv) * tanh_(gv);
            float h = sig_(ov) * tanh_(c);
            size_t oi = ((size_t)b * T + t) * HID + tid;
            if (out_f32) out_f32[oi] = h;
            else out_h16[oi] = f16b(h);
            ((ushort_t*)h32)[tid] = f16b(h);
        }
        __syncthreads();
    }
}

// ---------------- launch ----------------

extern "C" void kernel_launch(void* const* d_in, const int* in_sizes, int n_in,
                              void* d_out, int out_size, void* d_ws, size_t ws_size,
                              hipStream_t stream) {
    const float* x  = (const float*)d_in[0];
    const float* W0 = (const float*)d_in[1];
    const float* U0 = (const float*)d_in[2];
    const float* b0 = (const float*)d_in[3];
    const float* W1 = (const float*)d_in[4];
    const float* U1 = (const float*)d_in[5];
    const float* b1 = (const float*)d_in[6];
    float* out = (float*)d_out;

    const size_t M = (size_t)BATCH * SEQT;   // 32768

    char* ws = (char*)d_ws;
    ushort_t* xf16  = (ushort_t*)(ws);                        // 16 MB
    ushort_t* y1f16 = (ushort_t*)(ws + (16u << 20));          // 16 MB
    ushort_t* Wt0   = (ushort_t*)(ws + (32u << 20));          // 0.5 MB
    ushort_t* Wt1   = (ushort_t*)(ws + (32u << 20) + 524288); // 0.5 MB
    uint4*    Upk0  = (uint4*)   (ws + (33u << 20));          // 0.5 MB
    uint4*    Upk1  = (uint4*)   (ws + (33u << 20) + 524288); // 0.5 MB
    float*    xz    = (float*)   (ws + (34u << 20));          // 128 MB

    {
        int n4 = (int)(M * DIN / 4);
        cvt_x_kernel<<<dim3((n4 + 255) / 256), dim3(256), 0, stream>>>(x, xf16, n4);
        prep_wt_kernel<<<dim3(1024), dim3(256), 0, stream>>>(W0, Wt0);
        prep_wt_kernel<<<dim3(1024), dim3(256), 0, stream>>>(W1, Wt1);
        prep_upk_kernel<<<dim3(128), dim3(256), 0, stream>>>(U0, Upk0);
        prep_upk_kernel<<<dim3(128), dim3(256), 0, stream>>>(U1, Upk1);
    }

    // layer 1
    gemm_f16_kernel<<<dim3((int)(M / 128) * 8), dim3(256), 0, stream>>>(xf16, Wt0, b0, xz, (int)M);
    lstm_rec3_kernel<<<dim3(BATCH), dim3(512), 0, stream>>>(xz, Upk0, y1f16, nullptr, SEQT);

    // layer 2
    gemm_f16_kernel<<<dim3((int)(M / 128) * 8), dim3(256), 0, stream>>>(y1f16, Wt1, b1, xz, (int)M);
    lstm_rec3_kernel<<<dim3(BATCH), dim3(512), 0, stream>>>(xz, Upk1, nullptr, out, SEQT);
}